// Round 1
// 106.620 us; speedup vs baseline: 1.0244x; 1.0244x over previous
//
#include <hip/hip_runtime.h>

// VQ-VAE quantizer via MFMA on MI355X (gfx950).
// score(k) = x.e_k - 0.5||e_k||^2, argmax over K=512 codes per pixel.
// Augmented GEMM: A = ext codes [512 x 80] bf16 (dim 64 = -0.5||e||^2),
//                 B = [x, 1, 0...] per pixel -> mfma_f32_32x32x16_bf16.
// R3: fixed wave-stride bug (dur 108-109 us; vq_mfma itself ~22 us, the rest
//     is two 256 MiB harness poison-fills inside the timed graph).
// R4: (a) pixel pairing: lane's two groups are consecutive pixels -> float2
//         loads/stores (halves VMEM instrs in both HBM phases);
//     (b) packed argmax: acc init = 1.0f so scores are positive floats
//         (bit-monotonic as uint); candidate = (bits & ~511) | code, single
//         umax per candidate, 1 shfl + 1 umax half-merge;
//     (c) waves stay lockstep on t for L1 sharing of the A-rows.

typedef __bf16 bf16_t;
typedef __attribute__((ext_vector_type(8))) __bf16 bf16x8;
typedef __attribute__((ext_vector_type(16))) float floatx16;

namespace {
constexpr int K    = 512;
constexpr int D    = 64;
constexpr int HW   = 4096;
constexpr int NPIX = 32 * HW;       // 131072
constexpr int QOUT = NPIX * D;      // 8388608
constexpr int DEXT = 80;            // 64 dims + score-bias dim + pad (5 k-steps)
}

// Build augmented bf16 code table in ws; zero the loss slot.
__global__ __launch_bounds__(64) void vq_prep(const float* __restrict__ emb,
                                              bf16_t* __restrict__ ext,
                                              float* __restrict__ loss) {
    int k = blockIdx.x * 64 + threadIdx.x;
    if (k == 0) *loss = 0.0f;
    if (k >= K) return;
    const float4* row = (const float4*)(emb + k * D);
    float4 v[16];
#pragma unroll
    for (int i = 0; i < 16; ++i) v[i] = row[i];
    float s = 0.0f;
#pragma unroll
    for (int i = 0; i < 16; ++i)
        s += v[i].x * v[i].x + v[i].y * v[i].y + v[i].z * v[i].z + v[i].w * v[i].w;
    bf16_t r[DEXT];
#pragma unroll
    for (int i = 0; i < 16; ++i) {
        r[4 * i + 0] = (bf16_t)v[i].x;
        r[4 * i + 1] = (bf16_t)v[i].y;
        r[4 * i + 2] = (bf16_t)v[i].z;
        r[4 * i + 3] = (bf16_t)v[i].w;
    }
    r[64] = (bf16_t)(-0.5f * s);
#pragma unroll
    for (int i = 65; i < DEXT; ++i) r[i] = (bf16_t)0.0f;
#pragma unroll
    for (int i = 0; i < DEXT / 8; ++i)
        ((bf16x8*)(ext + k * DEXT))[i] = *(const bf16x8*)(r + 8 * i);
}

__global__ __launch_bounds__(256) void vq_mfma(
    const float* __restrict__ lat,
    const float* __restrict__ emb,
    const bf16_t* __restrict__ ext,
    float* __restrict__ out,
    float* __restrict__ loss) {
    const int lane = threadIdx.x & 63;
    const int wave = threadIdx.x >> 6;
    const int col  = lane & 31;       // pixel-pair id (B n) AND code row (A m)
    const int half = lane >> 5;       // k-group selector
    const unsigned h4 = (unsigned)(half << 2);   // code bit 2
    const int nb   = blockIdx.x * 256 + wave * 64;

    // Paired pixels: n0 = g=0, n0+1 = g=1. Same b, hw even -> float2 aligned.
    const int n0 = nb + 2 * col;
    const int b  = n0 >> 12;
    const int hw = n0 & (HW - 1);
    const float* latp = lat + (size_t)b * D * HW + hw;

    // B fragments (x in bf16; k = s*16 + half*8 + j).
    bf16x8 bfrag[2][5];
#pragma unroll
    for (int s = 0; s < 4; ++s) {
#pragma unroll
        for (int j = 0; j < 8; ++j) {
            int d = s * 16 + half * 8 + j;
            float2 v = *(const float2*)(latp + (size_t)d * HW);
            bfrag[0][s][j] = (bf16_t)v.x;
            bfrag[1][s][j] = (bf16_t)v.y;
        }
    }
#pragma unroll
    for (int j = 0; j < 8; ++j) {
        bfrag[0][4][j] = (bf16_t)0.0f;
        bfrag[1][4][j] = (bf16_t)0.0f;
    }
    if (half == 0) {                       // augmented dim 64 = 1
        bfrag[0][4][0] = (bf16_t)1.0f;
        bfrag[1][4][0] = (bf16_t)1.0f;
    }

    // Packed argmax state: high 23 bits = positive-score float bits, low 9 = code.
    unsigned best0 = 0u, best1 = 0u;

#pragma unroll 4
    for (int t = 0; t < 16; ++t) {
        const bf16_t* arow = ext + ((size_t)(t * 32 + col)) * DEXT + half * 8;
        bf16x8 af[5];
#pragma unroll
        for (int s = 0; s < 5; ++s) af[s] = *(const bf16x8*)(arow + s * 16);

        floatx16 acc0, acc1;
#pragma unroll
        for (int r = 0; r < 16; ++r) { acc0[r] = 1.0f; acc1[r] = 1.0f; }
#pragma unroll
        for (int s = 0; s < 5; ++s)
            acc0 = __builtin_amdgcn_mfma_f32_32x32x16_bf16(af[s], bfrag[0][s], acc0, 0, 0, 0);
#pragma unroll
        for (int s = 0; s < 5; ++s)
            acc1 = __builtin_amdgcn_mfma_f32_32x32x16_bf16(af[s], bfrag[1][s], acc1, 0, 0, 0);

#pragma unroll
        for (int r = 0; r < 16; ++r) {
            // code = t*32 (bits>=5) | roff (bits 0,1,3,4) | 4*half (bit 2) - disjoint.
            unsigned codebase = (unsigned)(t * 32 + ((r & 3) + 8 * (r >> 2)));
            unsigned c0 = (__float_as_uint(acc0[r]) & 0xFFFFFE00u) | codebase | h4;
            unsigned c1 = (__float_as_uint(acc1[r]) & 0xFFFFFE00u) | codebase | h4;
            best0 = best0 > c0 ? best0 : c0;
            best1 = best1 > c1 ? best1 : c1;
        }
    }

    // Merge the two half-wave code sets (same pixel col): 1 shfl + 1 umax each.
    {
        unsigned o0 = (unsigned)__shfl_xor((int)best0, 32, 64);
        unsigned o1 = (unsigned)__shfl_xor((int)best1, 32, 64);
        best0 = best0 > o0 ? best0 : o0;
        best1 = best1 > o1 ? best1 : o1;
    }
    const int k0 = (int)(best0 & 511u);
    const int k1 = (int)(best1 & 511u);

    // Gather winning codes (fp32), write transposed output as float2, loss.
    const float* e0 = emb + k0 * D + half * 8;
    const float* e1 = emb + k1 * D + half * 8;
    float* outp = out + (size_t)b * D * HW + hw;
    float sqtot = 0.0f;
#pragma unroll
    for (int s = 0; s < 4; ++s) {
        float4 a0 = *(const float4*)(e0 + s * 16);
        float4 a1 = *(const float4*)(e0 + s * 16 + 4);
        float4 c0 = *(const float4*)(e1 + s * 16);
        float4 c1 = *(const float4*)(e1 + s * 16 + 4);
        float q0[8] = {a0.x, a0.y, a0.z, a0.w, a1.x, a1.y, a1.z, a1.w};
        float q1[8] = {c0.x, c0.y, c0.z, c0.w, c1.x, c1.y, c1.z, c1.w};
#pragma unroll
        for (int j = 0; j < 8; ++j) {
            float x0 = (float)bfrag[0][s][j];
            float x1 = (float)bfrag[1][s][j];
            float d0 = q0[j] - x0;
            float d1 = q1[j] - x1;
            sqtot += d0 * d0 + d1 * d1;
            int d = s * 16 + half * 8 + j;
            *(float2*)(outp + (size_t)d * HW) = make_float2(q0[j], q1[j]);
        }
    }

    // wave reduce, block reduce, one atomic per block.
#pragma unroll
    for (int off = 32; off > 0; off >>= 1) sqtot += __shfl_down(sqtot, off, 64);
    __shared__ float part[4];
    if (lane == 0) part[wave] = sqtot;
    __syncthreads();
    if (threadIdx.x == 0) {
        float t = part[0] + part[1] + part[2] + part[3];
        atomicAdd(loss, t * (1.25f / (float)QOUT));
    }
}

extern "C" void kernel_launch(void* const* d_in, const int* in_sizes, int n_in,
                              void* d_out, int out_size, void* d_ws, size_t ws_size,
                              hipStream_t stream) {
    const float* lat = (const float*)d_in[0];
    const float* emb = (const float*)d_in[1];
    float* out       = (float*)d_out;
    float* loss      = out + QOUT;
    bf16_t* ext      = (bf16_t*)d_ws;   // 512*80*2 = 80 KB scratch

    vq_prep<<<K / 64, 64, 0, stream>>>(emb, ext, loss);
    // 64 px/wave (paired pixels, float2 I/O), 4 waves/block -> 256 px/block.
    vq_mfma<<<NPIX / 256, 256, 0, stream>>>(lat, emb, ext, out, loss);
}

// Round 3
// 102.494 us; speedup vs baseline: 1.0656x; 1.0403x over previous
//
#include <hip/hip_runtime.h>

// VQ-VAE quantizer via MFMA on MI355X (gfx950).
// score(k) = 1 + x.e_k - 0.5||e_k||^2 (positive -> bit-monotonic packed argmax).
// R5/R6: LDS-resident code table + T=2 tile pipeline per wave.
//     - ext table (bf16, 144B padded rows -> bank-even 8 dwords/bank per wave
//       b128 read) + fp32 (1-0.5||e||^2) bias table staged once per block into
//       74 KiB LDS via global_load_lds.
//     - t-loop consumes ONLY lgkmcnt (ds_read) -> tile-B latent loads stay in
//       flight on vmcnt across tile-A compute (vmcnt FIFO would otherwise drain).
//     - bias via accumulator init (broadcast ds_read_b128), aug k-step dropped:
//       4 MFMA k-steps instead of 5.
//     - loss from score: ||q-x||^2 = ||x||^2 - 2(score-1); gather only feeds the
//       output store and is issued one tile early (hidden under tile-B compute).
// R6 = R5 resubmitted verbatim after container infra failure (kernel audit
//      found no fault path; see journal).

typedef __bf16 bf16_t;
typedef __attribute__((ext_vector_type(8))) __bf16 bf16x8;
typedef __attribute__((ext_vector_type(16))) float floatx16;
typedef __attribute__((ext_vector_type(4))) float floatx4;

namespace {
constexpr int K    = 512;
constexpr int D    = 64;
constexpr int HW   = 4096;
constexpr int NPIX = 32 * HW;            // 131072
constexpr int QOUT = NPIX * D;           // 8388608
constexpr int ROWB = 144;                // padded row bytes (72 bf16: 64 data + 8 pad)
constexpr int EXT_BYTES  = K * ROWB;     // 73728
constexpr int BIAS_OFF   = EXT_BYTES;    // fp32[512] bias table after ext
constexpr int SMEM_BYTES = EXT_BYTES + K * 4;   // 75776 = 74 KiB
constexpr int SMEM_CHUNKS = SMEM_BYTES / 1024;  // 74 (exact)
}

// Build padded bf16 code table + fp32 (1 - 0.5||e||^2) table in ws; zero loss.
__global__ __launch_bounds__(64) void vq_prep(const float* __restrict__ emb,
                                              char* __restrict__ ws,
                                              float* __restrict__ loss) {
    int k = blockIdx.x * 64 + threadIdx.x;
    if (k == 0) *loss = 0.0f;
    if (k >= K) return;
    const float4* row = (const float4*)(emb + k * D);
    float4 v[16];
#pragma unroll
    for (int i = 0; i < 16; ++i) v[i] = row[i];
    float s = 0.0f;
#pragma unroll
    for (int i = 0; i < 16; ++i)
        s += v[i].x * v[i].x + v[i].y * v[i].y + v[i].z * v[i].z + v[i].w * v[i].w;
    bf16_t r[72];
#pragma unroll
    for (int i = 0; i < 16; ++i) {
        r[4 * i + 0] = (bf16_t)v[i].x;
        r[4 * i + 1] = (bf16_t)v[i].y;
        r[4 * i + 2] = (bf16_t)v[i].z;
        r[4 * i + 3] = (bf16_t)v[i].w;
    }
#pragma unroll
    for (int i = 64; i < 72; ++i) r[i] = (bf16_t)0.0f;
    bf16_t* dst = (bf16_t*)(ws + (size_t)k * ROWB);
#pragma unroll
    for (int i = 0; i < 9; ++i)
        ((bf16x8*)dst)[i] = *(const bf16x8*)(r + 8 * i);
    ((float*)(ws + BIAS_OFF))[k] = 1.0f - 0.5f * s;
}

__global__ __launch_bounds__(256) void vq_mfma(
    const float* __restrict__ lat,
    const float* __restrict__ emb,
    const char* __restrict__ wsrc,
    float* __restrict__ out,
    float* __restrict__ loss) {
    __shared__ char smem[SMEM_BYTES];

    const int lane = threadIdx.x & 63;
    const int wave = threadIdx.x >> 6;
    const int col  = lane & 31;
    const int half = lane >> 5;
    const unsigned h4 = (unsigned)(half << 2);

    // ---- stage ext + bias tables into LDS (global_load_lds, 1 KiB/wave-chunk) ----
    for (int c = wave; c < SMEM_CHUNKS; c += 4) {
        __builtin_amdgcn_global_load_lds(
            (const __attribute__((address_space(1))) unsigned int*)(wsrc + c * 1024 + lane * 16),
            (__attribute__((address_space(3))) unsigned int*)(smem + c * 1024),
            16, 0, 0);
    }
    __syncthreads();

    // Two consecutive 64-px tiles per wave (pair-per-lane -> float2 I/O).
    const int w  = blockIdx.x * 4 + wave;          // 0..1023
    const int n0 = w * 128 + 2 * col;              // tile A pixel pair; B at +64
    const int b  = n0 >> 12;
    const int hw = n0 & (HW - 1);                  // 128-px wave span stays in one b
    const float* latp = lat + (size_t)b * D * HW + hw;

    // ---- issue ALL latent loads (A then B) ----
    float2 rawA[32], rawB[32];
#pragma unroll
    for (int s = 0; s < 4; ++s)
#pragma unroll
        for (int j = 0; j < 8; ++j) {
            int d = s * 16 + half * 8 + j;
            rawA[s * 8 + j] = *(const float2*)(latp + (size_t)d * HW);
        }
#pragma unroll
    for (int s = 0; s < 4; ++s)
#pragma unroll
        for (int j = 0; j < 8; ++j) {
            int d = s * 16 + half * 8 + j;
            rawB[s * 8 + j] = *(const float2*)(latp + (size_t)d * HW + 64);
        }

    // ---- convert tile A (waits rawA only; rawB stays outstanding) ----
    bf16x8 bfA[2][4];
    float xsqA0 = 0.0f, xsqA1 = 0.0f;
#pragma unroll
    for (int s = 0; s < 4; ++s)
#pragma unroll
        for (int j = 0; j < 8; ++j) {
            float2 v = rawA[s * 8 + j];
            bfA[0][s][j] = (bf16_t)v.x;
            bfA[1][s][j] = (bf16_t)v.y;
            xsqA0 += v.x * v.x;
            xsqA1 += v.y * v.y;
        }

    // t-loop over 16 code blocks; LDS-only reads (lgkmcnt), packed uint argmax.
    auto tloop = [&](const bf16x8 (&bf)[2][4], unsigned& best0, unsigned& best1) {
        best0 = 0u; best1 = 0u;
#pragma unroll 2
        for (int t = 0; t < 16; ++t) {
            // bias init: broadcast reads of (1 - 0.5||e||^2) for this t-block.
            floatx4 bi[4];
#pragma unroll
            for (int c4 = 0; c4 < 4; ++c4)
                bi[c4] = *(const floatx4*)(smem + BIAS_OFF + t * 128 + half * 16 + c4 * 32);
            floatx16 acc0, acc1;
#pragma unroll
            for (int r = 0; r < 16; ++r) {
                float bv = bi[r >> 2][r & 3];
                acc0[r] = bv;
                acc1[r] = bv;
            }
            const char* arow = smem + (size_t)(t * 32 + col) * ROWB + half * 16;
            bf16x8 af[4];
#pragma unroll
            for (int s = 0; s < 4; ++s) af[s] = *(const bf16x8*)(arow + s * 32);
#pragma unroll
            for (int s = 0; s < 4; ++s) {
                acc0 = __builtin_amdgcn_mfma_f32_32x32x16_bf16(af[s], bf[0][s], acc0, 0, 0, 0);
                acc1 = __builtin_amdgcn_mfma_f32_32x32x16_bf16(af[s], bf[1][s], acc1, 0, 0, 0);
            }
#pragma unroll
            for (int r = 0; r < 16; ++r) {
                unsigned cb = (unsigned)(t * 32 + ((r & 3) + 8 * (r >> 2))) | h4;
                unsigned c0 = (__float_as_uint(acc0[r]) & 0xFFFFFE00u) | cb;
                unsigned c1 = (__float_as_uint(acc1[r]) & 0xFFFFFE00u) | cb;
                best0 = best0 > c0 ? best0 : c0;
                best1 = best1 > c1 ? best1 : c1;
            }
        }
        unsigned o0 = (unsigned)__shfl_xor((int)best0, 32, 64);
        unsigned o1 = (unsigned)__shfl_xor((int)best1, 32, 64);
        best0 = best0 > o0 ? best0 : o0;
        best1 = best1 > o1 ? best1 : o1;
    };

    // ---- tile A compute (rawB in flight under this) ----
    unsigned bestA0, bestA1;
    tloop(bfA, bestA0, bestA1);
    const int kA0 = (int)(bestA0 & 511u), kA1 = (int)(bestA1 & 511u);
    const float scA0 = __uint_as_float(bestA0 & 0xFFFFFE00u);
    const float scA1 = __uint_as_float(bestA1 & 0xFFFFFE00u);

    // ---- issue gather A (hidden under tile B compute) ----
    const float* eA0 = emb + kA0 * D + half * 8;
    const float* eA1 = emb + kA1 * D + half * 8;
    float4 qA0[8], qA1[8];
#pragma unroll
    for (int s = 0; s < 4; ++s) {
        qA0[2 * s]     = *(const float4*)(eA0 + s * 16);
        qA0[2 * s + 1] = *(const float4*)(eA0 + s * 16 + 4);
        qA1[2 * s]     = *(const float4*)(eA1 + s * 16);
        qA1[2 * s + 1] = *(const float4*)(eA1 + s * 16 + 4);
    }

    // ---- convert tile B ----
    bf16x8 bfB[2][4];
    float xsqB0 = 0.0f, xsqB1 = 0.0f;
#pragma unroll
    for (int s = 0; s < 4; ++s)
#pragma unroll
        for (int j = 0; j < 8; ++j) {
            float2 v = rawB[s * 8 + j];
            bfB[0][s][j] = (bf16_t)v.x;
            bfB[1][s][j] = (bf16_t)v.y;
            xsqB0 += v.x * v.x;
            xsqB1 += v.y * v.y;
        }

    // ---- tile B compute (gather A in flight under this) ----
    unsigned bestB0, bestB1;
    tloop(bfB, bestB0, bestB1);
    const int kB0 = (int)(bestB0 & 511u), kB1 = (int)(bestB1 & 511u);
    const float scB0 = __uint_as_float(bestB0 & 0xFFFFFE00u);
    const float scB1 = __uint_as_float(bestB1 & 0xFFFFFE00u);

    // ---- store tile A ----
    float* outpA = out + (size_t)b * D * HW + hw;
#pragma unroll
    for (int s = 0; s < 4; ++s)
#pragma unroll
        for (int j = 0; j < 8; ++j) {
            int d = s * 16 + half * 8 + j;
            float a = (j < 4) ? qA0[2 * s][j] : qA0[2 * s + 1][j - 4];
            float c = (j < 4) ? qA1[2 * s][j] : qA1[2 * s + 1][j - 4];
            *(float2*)(outpA + (size_t)d * HW) = make_float2(a, c);
        }

    // ---- gather + store tile B ----
    const float* eB0 = emb + kB0 * D + half * 8;
    const float* eB1 = emb + kB1 * D + half * 8;
    float4 qB0[8], qB1[8];
#pragma unroll
    for (int s = 0; s < 4; ++s) {
        qB0[2 * s]     = *(const float4*)(eB0 + s * 16);
        qB0[2 * s + 1] = *(const float4*)(eB0 + s * 16 + 4);
        qB1[2 * s]     = *(const float4*)(eB1 + s * 16);
        qB1[2 * s + 1] = *(const float4*)(eB1 + s * 16 + 4);
    }
    float* outpB = outpA + 64;
#pragma unroll
    for (int s = 0; s < 4; ++s)
#pragma unroll
        for (int j = 0; j < 8; ++j) {
            int d = s * 16 + half * 8 + j;
            float a = (j < 4) ? qB0[2 * s][j] : qB0[2 * s + 1][j - 4];
            float c = (j < 4) ? qB1[2 * s][j] : qB1[2 * s + 1][j - 4];
            *(float2*)(outpB + (size_t)d * HW) = make_float2(a, c);
        }

    // ---- loss: ||q-x||^2 = ||x||^2 - 2(score-1); halves double-count -> x0.5 ----
    float xsqA0f = xsqA0 + __shfl_xor(xsqA0, 32, 64);
    float xsqA1f = xsqA1 + __shfl_xor(xsqA1, 32, 64);
    float xsqB0f = xsqB0 + __shfl_xor(xsqB0, 32, 64);
    float xsqB1f = xsqB1 + __shfl_xor(xsqB1, 32, 64);
    float sqtot = (xsqA0f - 2.0f * (scA0 - 1.0f)) + (xsqA1f - 2.0f * (scA1 - 1.0f))
                + (xsqB0f - 2.0f * (scB0 - 1.0f)) + (xsqB1f - 2.0f * (scB1 - 1.0f));
    sqtot *= 0.5f;

#pragma unroll
    for (int off = 32; off > 0; off >>= 1) sqtot += __shfl_down(sqtot, off, 64);
    __shared__ float part[4];
    if (lane == 0) part[wave] = sqtot;
    __syncthreads();
    if (threadIdx.x == 0) {
        float t = part[0] + part[1] + part[2] + part[3];
        atomicAdd(loss, t * (1.25f / (float)QOUT));
    }
}

extern "C" void kernel_launch(void* const* d_in, const int* in_sizes, int n_in,
                              void* d_out, int out_size, void* d_ws, size_t ws_size,
                              hipStream_t stream) {
    const float* lat = (const float*)d_in[0];
    const float* emb = (const float*)d_in[1];
    float* out       = (float*)d_out;
    float* loss      = out + QOUT;
    char* ws         = (char*)d_ws;   // 74 KiB: padded code table + bias table

    vq_prep<<<K / 64, 64, 0, stream>>>(emb, ws, loss);
    // 256 blocks x 4 waves; each wave: 2 consecutive 64-px tiles, pipelined.
    vq_mfma<<<256, 256, 0, stream>>>(lat, emb, ws, out, loss);
}

// Round 4
// 102.312 us; speedup vs baseline: 1.0675x; 1.0018x over previous
//
#include <hip/hip_runtime.h>

// VQ-VAE quantizer via MFMA on MI355X (gfx950).
// score(k) = 1 + x.e_k - 0.5||e_k||^2 (positive -> bit-monotonic packed argmax).
// R5/R6: LDS-resident code table (144B padded rows, bank-even) + bias-as-acc-init
//     (4 MFMA k-steps) + T=2 tile pipeline per wave + loss from score identity.
//     vq_mfma ~15.4 us vs 10.6 us combined-HBM floor.
// R7: hide the write burst. All blocks share one phase timeline, so tile stores
//     formed a fully-exposed ~5.3 us device-wide write phase at the end.
//     Tile-A stores are now woven into tloopB iterations t=2..9 (4 float2/iter,
//     fire-and-forget; issued after gatherA so compiler emits growing counted
//     vmcnt, no FIFO drain). Tile-A write BW flows under tile-B compute.
//     Tile-B stores stay at the tail (~2.65 us exposed).

typedef __bf16 bf16_t;
typedef __attribute__((ext_vector_type(8))) __bf16 bf16x8;
typedef __attribute__((ext_vector_type(16))) float floatx16;
typedef __attribute__((ext_vector_type(4))) float floatx4;

namespace {
constexpr int K    = 512;
constexpr int D    = 64;
constexpr int HW   = 4096;
constexpr int NPIX = 32 * HW;            // 131072
constexpr int QOUT = NPIX * D;           // 8388608
constexpr int ROWB = 144;                // padded row bytes (72 bf16: 64 data + 8 pad)
constexpr int EXT_BYTES  = K * ROWB;     // 73728
constexpr int BIAS_OFF   = EXT_BYTES;    // fp32[512] bias table after ext
constexpr int SMEM_BYTES = EXT_BYTES + K * 4;   // 75776 = 74 KiB
constexpr int SMEM_CHUNKS = SMEM_BYTES / 1024;  // 74 (exact)
}

// Build padded bf16 code table + fp32 (1 - 0.5||e||^2) table in ws; zero loss.
__global__ __launch_bounds__(64) void vq_prep(const float* __restrict__ emb,
                                              char* __restrict__ ws,
                                              float* __restrict__ loss) {
    int k = blockIdx.x * 64 + threadIdx.x;
    if (k == 0) *loss = 0.0f;
    if (k >= K) return;
    const float4* row = (const float4*)(emb + k * D);
    float4 v[16];
#pragma unroll
    for (int i = 0; i < 16; ++i) v[i] = row[i];
    float s = 0.0f;
#pragma unroll
    for (int i = 0; i < 16; ++i)
        s += v[i].x * v[i].x + v[i].y * v[i].y + v[i].z * v[i].z + v[i].w * v[i].w;
    bf16_t r[72];
#pragma unroll
    for (int i = 0; i < 16; ++i) {
        r[4 * i + 0] = (bf16_t)v[i].x;
        r[4 * i + 1] = (bf16_t)v[i].y;
        r[4 * i + 2] = (bf16_t)v[i].z;
        r[4 * i + 3] = (bf16_t)v[i].w;
    }
#pragma unroll
    for (int i = 64; i < 72; ++i) r[i] = (bf16_t)0.0f;
    bf16_t* dst = (bf16_t*)(ws + (size_t)k * ROWB);
#pragma unroll
    for (int i = 0; i < 9; ++i)
        ((bf16x8*)dst)[i] = *(const bf16x8*)(r + 8 * i);
    ((float*)(ws + BIAS_OFF))[k] = 1.0f - 0.5f * s;
}

__global__ __launch_bounds__(256) void vq_mfma(
    const float* __restrict__ lat,
    const float* __restrict__ emb,
    const char* __restrict__ wsrc,
    float* __restrict__ out,
    float* __restrict__ loss) {
    __shared__ char smem[SMEM_BYTES];

    const int lane = threadIdx.x & 63;
    const int wave = threadIdx.x >> 6;
    const int col  = lane & 31;
    const int half = lane >> 5;
    const unsigned h4 = (unsigned)(half << 2);

    // ---- stage ext + bias tables into LDS (global_load_lds, 1 KiB/wave-chunk) ----
    for (int c = wave; c < SMEM_CHUNKS; c += 4) {
        __builtin_amdgcn_global_load_lds(
            (const __attribute__((address_space(1))) unsigned int*)(wsrc + c * 1024 + lane * 16),
            (__attribute__((address_space(3))) unsigned int*)(smem + c * 1024),
            16, 0, 0);
    }
    __syncthreads();

    // Two consecutive 64-px tiles per wave (pair-per-lane -> float2 I/O).
    const int w  = blockIdx.x * 4 + wave;          // 0..1023
    const int n0 = w * 128 + 2 * col;              // tile A pixel pair; B at +64
    const int b  = n0 >> 12;
    const int hw = n0 & (HW - 1);                  // 128-px wave span stays in one b
    const float* latp = lat + (size_t)b * D * HW + hw;

    // ---- issue ALL latent loads (A then B) ----
    float2 rawA[32], rawB[32];
#pragma unroll
    for (int s = 0; s < 4; ++s)
#pragma unroll
        for (int j = 0; j < 8; ++j) {
            int d = s * 16 + half * 8 + j;
            rawA[s * 8 + j] = *(const float2*)(latp + (size_t)d * HW);
        }
#pragma unroll
    for (int s = 0; s < 4; ++s)
#pragma unroll
        for (int j = 0; j < 8; ++j) {
            int d = s * 16 + half * 8 + j;
            rawB[s * 8 + j] = *(const float2*)(latp + (size_t)d * HW + 64);
        }

    // ---- convert tile A (waits rawA only; rawB stays outstanding) ----
    bf16x8 bfA[2][4];
    float xsqA0 = 0.0f, xsqA1 = 0.0f;
#pragma unroll
    for (int s = 0; s < 4; ++s)
#pragma unroll
        for (int j = 0; j < 8; ++j) {
            float2 v = rawA[s * 8 + j];
            bfA[0][s][j] = (bf16_t)v.x;
            bfA[1][s][j] = (bf16_t)v.y;
            xsqA0 += v.x * v.x;
            xsqA1 += v.y * v.y;
        }

    // One t-step: bias-init accs, 4 MFMA k-steps for both pixels, packed argmax.
    auto tstep = [&](int t, const bf16x8 (&bf)[2][4], unsigned& best0, unsigned& best1) {
        floatx4 bi[4];
#pragma unroll
        for (int c4 = 0; c4 < 4; ++c4)
            bi[c4] = *(const floatx4*)(smem + BIAS_OFF + t * 128 + half * 16 + c4 * 32);
        floatx16 acc0, acc1;
#pragma unroll
        for (int r = 0; r < 16; ++r) {
            float bv = bi[r >> 2][r & 3];
            acc0[r] = bv;
            acc1[r] = bv;
        }
        const char* arow = smem + (size_t)(t * 32 + col) * ROWB + half * 16;
        bf16x8 af[4];
#pragma unroll
        for (int s = 0; s < 4; ++s) af[s] = *(const bf16x8*)(arow + s * 32);
#pragma unroll
        for (int s = 0; s < 4; ++s) {
            acc0 = __builtin_amdgcn_mfma_f32_32x32x16_bf16(af[s], bf[0][s], acc0, 0, 0, 0);
            acc1 = __builtin_amdgcn_mfma_f32_32x32x16_bf16(af[s], bf[1][s], acc1, 0, 0, 0);
        }
#pragma unroll
        for (int r = 0; r < 16; ++r) {
            unsigned cb = (unsigned)(t * 32 + ((r & 3) + 8 * (r >> 2))) | h4;
            unsigned c0 = (__float_as_uint(acc0[r]) & 0xFFFFFE00u) | cb;
            unsigned c1 = (__float_as_uint(acc1[r]) & 0xFFFFFE00u) | cb;
            best0 = best0 > c0 ? best0 : c0;
            best1 = best1 > c1 ? best1 : c1;
        }
    };
    auto merge = [&](unsigned& best0, unsigned& best1) {
        unsigned o0 = (unsigned)__shfl_xor((int)best0, 32, 64);
        unsigned o1 = (unsigned)__shfl_xor((int)best1, 32, 64);
        best0 = best0 > o0 ? best0 : o0;
        best1 = best1 > o1 ? best1 : o1;
    };

    // ---- tile A compute (rawB in flight under this) ----
    unsigned bestA0 = 0u, bestA1 = 0u;
#pragma unroll 2
    for (int t = 0; t < 16; ++t) tstep(t, bfA, bestA0, bestA1);
    merge(bestA0, bestA1);
    const int kA0 = (int)(bestA0 & 511u), kA1 = (int)(bestA1 & 511u);
    const float scA0 = __uint_as_float(bestA0 & 0xFFFFFE00u);
    const float scA1 = __uint_as_float(bestA1 & 0xFFFFFE00u);

    // ---- issue gather A (lands during convB / early tloopB) ----
    const float* eA0 = emb + kA0 * D + half * 8;
    const float* eA1 = emb + kA1 * D + half * 8;
    float4 qA0[8], qA1[8];
#pragma unroll
    for (int s = 0; s < 4; ++s) {
        qA0[2 * s]     = *(const float4*)(eA0 + s * 16);
        qA0[2 * s + 1] = *(const float4*)(eA0 + s * 16 + 4);
        qA1[2 * s]     = *(const float4*)(eA1 + s * 16);
        qA1[2 * s + 1] = *(const float4*)(eA1 + s * 16 + 4);
    }

    // ---- convert tile B ----
    bf16x8 bfB[2][4];
    float xsqB0 = 0.0f, xsqB1 = 0.0f;
#pragma unroll
    for (int s = 0; s < 4; ++s)
#pragma unroll
        for (int j = 0; j < 8; ++j) {
            float2 v = rawB[s * 8 + j];
            bfB[0][s][j] = (bf16_t)v.x;
            bfB[1][s][j] = (bf16_t)v.y;
            xsqB0 += v.x * v.x;
            xsqB1 += v.y * v.y;
        }

    // ---- tile B compute with tile-A stores woven in (t=2..9, 4 float2/iter) ----
    float* outpA = out + (size_t)b * D * HW + hw;
    auto storeg = [&](int g) {   // g in [0,8): one float4-pair of tile A
        int s = g >> 1, jh = g & 1;
        float4 a0 = qA0[2 * s + jh];
        float4 a1 = qA1[2 * s + jh];
        int dbase = s * 16 + half * 8 + jh * 4;
        *(float2*)(outpA + (size_t)(dbase + 0) * HW) = make_float2(a0.x, a1.x);
        *(float2*)(outpA + (size_t)(dbase + 1) * HW) = make_float2(a0.y, a1.y);
        *(float2*)(outpA + (size_t)(dbase + 2) * HW) = make_float2(a0.z, a1.z);
        *(float2*)(outpA + (size_t)(dbase + 3) * HW) = make_float2(a0.w, a1.w);
    };

    unsigned bestB0 = 0u, bestB1 = 0u;
#pragma unroll
    for (int t = 0; t < 2; ++t) tstep(t, bfB, bestB0, bestB1);
#pragma unroll
    for (int t = 2; t < 10; ++t) {
        tstep(t, bfB, bestB0, bestB1);
        storeg(t - 2);
    }
#pragma unroll 2
    for (int t = 10; t < 16; ++t) tstep(t, bfB, bestB0, bestB1);
    merge(bestB0, bestB1);
    const int kB0 = (int)(bestB0 & 511u), kB1 = (int)(bestB1 & 511u);
    const float scB0 = __uint_as_float(bestB0 & 0xFFFFFE00u);
    const float scB1 = __uint_as_float(bestB1 & 0xFFFFFE00u);

    // ---- gather + store tile B (tail; drains at kernel end) ----
    const float* eB0 = emb + kB0 * D + half * 8;
    const float* eB1 = emb + kB1 * D + half * 8;
    float* outpB = outpA + 64;
#pragma unroll
    for (int s = 0; s < 4; ++s) {
#pragma unroll
        for (int jh = 0; jh < 2; ++jh) {
            float4 a0 = *(const float4*)(eB0 + s * 16 + jh * 4);
            float4 a1 = *(const float4*)(eB1 + s * 16 + jh * 4);
            int dbase = s * 16 + half * 8 + jh * 4;
            *(float2*)(outpB + (size_t)(dbase + 0) * HW) = make_float2(a0.x, a1.x);
            *(float2*)(outpB + (size_t)(dbase + 1) * HW) = make_float2(a0.y, a1.y);
            *(float2*)(outpB + (size_t)(dbase + 2) * HW) = make_float2(a0.z, a1.z);
            *(float2*)(outpB + (size_t)(dbase + 3) * HW) = make_float2(a0.w, a1.w);
        }
    }

    // ---- loss: ||q-x||^2 = ||x||^2 - 2(score-1); halves double-count -> x0.5 ----
    float xsqA0f = xsqA0 + __shfl_xor(xsqA0, 32, 64);
    float xsqA1f = xsqA1 + __shfl_xor(xsqA1, 32, 64);
    float xsqB0f = xsqB0 + __shfl_xor(xsqB0, 32, 64);
    float xsqB1f = xsqB1 + __shfl_xor(xsqB1, 32, 64);
    float sqtot = (xsqA0f - 2.0f * (scA0 - 1.0f)) + (xsqA1f - 2.0f * (scA1 - 1.0f))
                + (xsqB0f - 2.0f * (scB0 - 1.0f)) + (xsqB1f - 2.0f * (scB1 - 1.0f));
    sqtot *= 0.5f;

#pragma unroll
    for (int off = 32; off > 0; off >>= 1) sqtot += __shfl_down(sqtot, off, 64);
    __shared__ float part[4];
    if (lane == 0) part[wave] = sqtot;
    __syncthreads();
    if (threadIdx.x == 0) {
        float t = part[0] + part[1] + part[2] + part[3];
        atomicAdd(loss, t * (1.25f / (float)QOUT));
    }
}

extern "C" void kernel_launch(void* const* d_in, const int* in_sizes, int n_in,
                              void* d_out, int out_size, void* d_ws, size_t ws_size,
                              hipStream_t stream) {
    const float* lat = (const float*)d_in[0];
    const float* emb = (const float*)d_in[1];
    float* out       = (float*)d_out;
    float* loss      = out + QOUT;
    char* ws         = (char*)d_ws;   // 74 KiB: padded code table + bias table

    vq_prep<<<K / 64, 64, 0, stream>>>(emb, ws, loss);
    // 256 blocks x 4 waves; each wave: 2 consecutive 64-px tiles, pipelined;
    // tile-A stores interleaved into tile-B compute.
    vq_mfma<<<256, 256, 0, stream>>>(lat, emb, ws, out, loss);
}

// Round 5
// 100.421 us; speedup vs baseline: 1.0876x; 1.0188x over previous
//
#include <hip/hip_runtime.h>

// VQ-VAE quantizer via MFMA on MI355X (gfx950).
// score(k) = 1 + x.e_k - 0.5||e_k||^2 (positive -> bit-monotonic packed argmax).
// R5/R6: LDS-resident code table (144B padded rows, bank-even) + bias-as-acc-init
//     (4 MFMA k-steps) + T=2 in-wave tile pipeline. vq_mfma ~15.4 us.
// R7: store-weave into tloopB -> FLAT. Post-mortem: 256x256 grid = 1 wave/SIMD;
//     intra-wave reordering can't overlap anything at occupancy 1.
// R8: occupancy fix. 256 blocks x 512 threads (8 waves), one 64-px tile per
//     wave, T=1. 2 waves/SIMD -> TLP hides lgkm/vmcnt stalls and overlaps one
//     wave's t-loop with the other's load/gather/store bursts. VGPR roughly
//     halves (no rawB/qB double buffer).

typedef __bf16 bf16_t;
typedef __attribute__((ext_vector_type(8))) __bf16 bf16x8;
typedef __attribute__((ext_vector_type(16))) float floatx16;
typedef __attribute__((ext_vector_type(4))) float floatx4;

namespace {
constexpr int K    = 512;
constexpr int D    = 64;
constexpr int HW   = 4096;
constexpr int NPIX = 32 * HW;            // 131072
constexpr int QOUT = NPIX * D;           // 8388608
constexpr int ROWB = 144;                // padded row bytes (72 bf16: 64 data + 8 pad)
constexpr int EXT_BYTES  = K * ROWB;     // 73728
constexpr int BIAS_OFF   = EXT_BYTES;    // fp32[512] bias table after ext
constexpr int SMEM_BYTES = EXT_BYTES + K * 4;   // 75776 = 74 KiB
constexpr int SMEM_CHUNKS = SMEM_BYTES / 1024;  // 74 (exact)
}

// Build padded bf16 code table + fp32 (1 - 0.5||e||^2) table in ws; zero loss.
__global__ __launch_bounds__(64) void vq_prep(const float* __restrict__ emb,
                                              char* __restrict__ ws,
                                              float* __restrict__ loss) {
    int k = blockIdx.x * 64 + threadIdx.x;
    if (k == 0) *loss = 0.0f;
    if (k >= K) return;
    const float4* row = (const float4*)(emb + k * D);
    float4 v[16];
#pragma unroll
    for (int i = 0; i < 16; ++i) v[i] = row[i];
    float s = 0.0f;
#pragma unroll
    for (int i = 0; i < 16; ++i)
        s += v[i].x * v[i].x + v[i].y * v[i].y + v[i].z * v[i].z + v[i].w * v[i].w;
    bf16_t r[72];
#pragma unroll
    for (int i = 0; i < 16; ++i) {
        r[4 * i + 0] = (bf16_t)v[i].x;
        r[4 * i + 1] = (bf16_t)v[i].y;
        r[4 * i + 2] = (bf16_t)v[i].z;
        r[4 * i + 3] = (bf16_t)v[i].w;
    }
#pragma unroll
    for (int i = 64; i < 72; ++i) r[i] = (bf16_t)0.0f;
    bf16_t* dst = (bf16_t*)(ws + (size_t)k * ROWB);
#pragma unroll
    for (int i = 0; i < 9; ++i)
        ((bf16x8*)dst)[i] = *(const bf16x8*)(r + 8 * i);
    ((float*)(ws + BIAS_OFF))[k] = 1.0f - 0.5f * s;
}

__global__ __launch_bounds__(512) void vq_mfma(
    const float* __restrict__ lat,
    const float* __restrict__ emb,
    const char* __restrict__ wsrc,
    float* __restrict__ out,
    float* __restrict__ loss) {
    __shared__ char smem[SMEM_BYTES];

    const int lane = threadIdx.x & 63;
    const int wave = threadIdx.x >> 6;        // 0..7
    const int col  = lane & 31;
    const int half = lane >> 5;
    const unsigned h4 = (unsigned)(half << 2);

    // ---- stage ext + bias tables into LDS (global_load_lds, 1 KiB/wave-chunk) ----
    for (int c = wave; c < SMEM_CHUNKS; c += 8) {
        __builtin_amdgcn_global_load_lds(
            (const __attribute__((address_space(1))) unsigned int*)(wsrc + c * 1024 + lane * 16),
            (__attribute__((address_space(3))) unsigned int*)(smem + c * 1024),
            16, 0, 0);
    }
    __syncthreads();

    // One 64-px tile per wave; pixel pair per lane -> float2 I/O.
    const int w  = blockIdx.x * 8 + wave;      // 0..2047
    const int n0 = w * 64 + 2 * col;
    const int b  = n0 >> 12;
    const int hw = n0 & (HW - 1);              // 64-px tile stays in one b
    const float* latp = lat + (size_t)b * D * HW + hw;

    // ---- latent loads ----
    float2 raw[32];
#pragma unroll
    for (int s = 0; s < 4; ++s)
#pragma unroll
        for (int j = 0; j < 8; ++j) {
            int d = s * 16 + half * 8 + j;
            raw[s * 8 + j] = *(const float2*)(latp + (size_t)d * HW);
        }

    // ---- convert + ||x||^2 ----
    bf16x8 bf[2][4];
    float xsq0 = 0.0f, xsq1 = 0.0f;
#pragma unroll
    for (int s = 0; s < 4; ++s)
#pragma unroll
        for (int j = 0; j < 8; ++j) {
            float2 v = raw[s * 8 + j];
            bf[0][s][j] = (bf16_t)v.x;
            bf[1][s][j] = (bf16_t)v.y;
            xsq0 += v.x * v.x;
            xsq1 += v.y * v.y;
        }

    // ---- t-loop: bias-init accs, 4 MFMA k-steps x 2 pixels, packed argmax ----
    unsigned best0 = 0u, best1 = 0u;
#pragma unroll 2
    for (int t = 0; t < 16; ++t) {
        floatx4 bi[4];
#pragma unroll
        for (int c4 = 0; c4 < 4; ++c4)
            bi[c4] = *(const floatx4*)(smem + BIAS_OFF + t * 128 + half * 16 + c4 * 32);
        floatx16 acc0, acc1;
#pragma unroll
        for (int r = 0; r < 16; ++r) {
            float bv = bi[r >> 2][r & 3];
            acc0[r] = bv;
            acc1[r] = bv;
        }
        const char* arow = smem + (size_t)(t * 32 + col) * ROWB + half * 16;
        bf16x8 af[4];
#pragma unroll
        for (int s = 0; s < 4; ++s) af[s] = *(const bf16x8*)(arow + s * 32);
#pragma unroll
        for (int s = 0; s < 4; ++s) {
            acc0 = __builtin_amdgcn_mfma_f32_32x32x16_bf16(af[s], bf[0][s], acc0, 0, 0, 0);
            acc1 = __builtin_amdgcn_mfma_f32_32x32x16_bf16(af[s], bf[1][s], acc1, 0, 0, 0);
        }
#pragma unroll
        for (int r = 0; r < 16; ++r) {
            unsigned cb = (unsigned)(t * 32 + ((r & 3) + 8 * (r >> 2))) | h4;
            unsigned c0 = (__float_as_uint(acc0[r]) & 0xFFFFFE00u) | cb;
            unsigned c1 = (__float_as_uint(acc1[r]) & 0xFFFFFE00u) | cb;
            best0 = best0 > c0 ? best0 : c0;
            best1 = best1 > c1 ? best1 : c1;
        }
    }
    {   // merge half-wave row sets
        unsigned o0 = (unsigned)__shfl_xor((int)best0, 32, 64);
        unsigned o1 = (unsigned)__shfl_xor((int)best1, 32, 64);
        best0 = best0 > o0 ? best0 : o0;
        best1 = best1 > o1 ? best1 : o1;
    }
    const int k0 = (int)(best0 & 511u);
    const int k1 = (int)(best1 & 511u);
    const float sc0 = __uint_as_float(best0 & 0xFFFFFE00u);
    const float sc1 = __uint_as_float(best1 & 0xFFFFFE00u);

    // ---- gather winning codes + store transposed float2 ----
    const float* e0 = emb + k0 * D + half * 8;
    const float* e1 = emb + k1 * D + half * 8;
    float* outp = out + (size_t)b * D * HW + hw;
#pragma unroll
    for (int s = 0; s < 4; ++s) {
#pragma unroll
        for (int jh = 0; jh < 2; ++jh) {
            float4 a0 = *(const float4*)(e0 + s * 16 + jh * 4);
            float4 a1 = *(const float4*)(e1 + s * 16 + jh * 4);
            int dbase = s * 16 + half * 8 + jh * 4;
            *(float2*)(outp + (size_t)(dbase + 0) * HW) = make_float2(a0.x, a1.x);
            *(float2*)(outp + (size_t)(dbase + 1) * HW) = make_float2(a0.y, a1.y);
            *(float2*)(outp + (size_t)(dbase + 2) * HW) = make_float2(a0.z, a1.z);
            *(float2*)(outp + (size_t)(dbase + 3) * HW) = make_float2(a0.w, a1.w);
        }
    }

    // ---- loss: ||q-x||^2 = ||x||^2 - 2(score-1); halves double-count -> x0.5 ----
    float xsq0f = xsq0 + __shfl_xor(xsq0, 32, 64);
    float xsq1f = xsq1 + __shfl_xor(xsq1, 32, 64);
    float sqtot = (xsq0f - 2.0f * (sc0 - 1.0f)) + (xsq1f - 2.0f * (sc1 - 1.0f));
    sqtot *= 0.5f;

#pragma unroll
    for (int off = 32; off > 0; off >>= 1) sqtot += __shfl_down(sqtot, off, 64);
    __shared__ float part[8];
    if (lane == 0) part[wave] = sqtot;
    __syncthreads();
    if (threadIdx.x == 0) {
        float t = 0.0f;
#pragma unroll
        for (int i = 0; i < 8; ++i) t += part[i];
        atomicAdd(loss, t * (1.25f / (float)QOUT));
    }
}

extern "C" void kernel_launch(void* const* d_in, const int* in_sizes, int n_in,
                              void* d_out, int out_size, void* d_ws, size_t ws_size,
                              hipStream_t stream) {
    const float* lat = (const float*)d_in[0];
    const float* emb = (const float*)d_in[1];
    float* out       = (float*)d_out;
    float* loss      = out + QOUT;
    char* ws         = (char*)d_ws;   // 74 KiB: padded code table + bias table

    vq_prep<<<K / 64, 64, 0, stream>>>(emb, ws, loss);
    // 256 blocks x 8 waves; one 64-px tile per wave -> 2 waves/SIMD (TLP).
    vq_mfma<<<NPIX / 512, 512, 0, stream>>>(lat, emb, ws, out, loss);
}